// Round 5
// baseline (1164.607 us; speedup 1.0000x reference)
//
#include <hip/hip_runtime.h>
#include <stdint.h>

// ---------------------------------------------------------------------------
// Types / helpers
// ---------------------------------------------------------------------------
typedef float  f32x4  __attribute__((ext_vector_type(4)));
typedef __bf16 bf16x8 __attribute__((ext_vector_type(8)));
typedef short  s16x8  __attribute__((ext_vector_type(8)));

#define DEV __device__ __forceinline__

DEV short f2b(float f) {  // fp32 -> bf16 bits, round-to-nearest-even
    union { float f; unsigned u; } c; c.f = f;
    unsigned u = c.u;
    unsigned r = (u + 0x7fffu + ((u >> 16) & 1u)) >> 16;
    return (short)r;
}
DEV float b2f(short s) {
    union { unsigned u; float f; } c; c.u = ((unsigned)(unsigned short)s) << 16;
    return c.f;
}

DEV void gload_lds16(const void* g, void* l) {
    // async global->LDS, 16B per lane; LDS dest = wave-uniform base + lane*16
    __builtin_amdgcn_global_load_lds(
        (const __attribute__((address_space(1))) void*)g,
        (__attribute__((address_space(3))) void*)l, 16, 0, 0);
}

// ---------------------------------------------------------------------------
// GEMM: C = A(bf16,[M,K]) * B(bf16, stored as B^T [N,K]) with fused epilogues.
// 64x64 tiles, DEPTH-2 pipeline with counted vmcnt (T3/T4): 3 LDS buffers,
// stage(t+2) issued at top of iter t, steady-state wait is vmcnt(4) (one
// stage = 4 loads/thread stays in flight ACROSS the barrier; never drains
// to 0 in the main loop). LDS XOR-swizzled via pre-swizzled global source.
// MODE 1: +bias, scatter q(*0.125)/k to [B,H,N,64], v to [B,H,64,N] (V^T)
// MODE 2: +bias, exact GELU, out bf16 row-major                [FFN1]
// MODE 3: fp32 partial store per split (no bias)               [FFN2 split-K]
// ---------------------------------------------------------------------------
template<int BM, int BN, int MODE, int NSPLIT>
__global__ __launch_bounds__(256) void gemm_bt(
    const short* __restrict__ A, const short* __restrict__ Bt,
    const float* __restrict__ bias,
    float* __restrict__ outf, short* __restrict__ outs0,
    short* __restrict__ outs1, short* __restrict__ outs2,
    long sA, long sB, long sO, int M, int N, int K)
{
    constexpr int BK = 64;
    constexpr int FM = BM / 32, FN = BN / 32;
    static_assert((BM + BN) / 32 == 4, "vmcnt(4) assumes 4 loads per stage");
    __shared__ __align__(16) short As[3][BM * BK];
    __shared__ __align__(16) short Bs[3][BN * BK];

    const int tid  = threadIdx.x;
    const int w    = tid >> 6, lane = tid & 63;
    const int wr   = w >> 1,  wc   = w & 1;
    const int l16  = lane & 15, lhi = lane >> 4, sw = lane & 7;

    // bijective XCD-aware remap of the (x,y) grid (all grids have nwg%8==0)
    const int gx   = gridDim.x;
    const int nwg  = gx * gridDim.y;
    const int flat = blockIdx.y * gx + blockIdx.x;
    const int nf   = (flat & 7) * (nwg >> 3) + (flat >> 3);
    const int bx   = nf % gx, by = nf / gx;

    int z, kz;
    if constexpr (NSPLIT > 1) { z = 0; kz = blockIdx.z; }
    else                      { z = blockIdx.z; kz = 0; }

    const short* Ab = A  + (long)z * sA + (long)by * BM * K;
    const short* Bb = Bt + (long)z * sB + (long)bx * BN * K;

    const int ktPer = (K >> 6) / NSPLIT;
    const int ktBeg = kz * ktPer, ktEnd = ktBeg + ktPer;

    f32x4 acc[FM][FN];
#pragma unroll
    for (int m = 0; m < FM; ++m)
#pragma unroll
        for (int n = 0; n < FN; ++n) acc[m][n] = (f32x4)(0.0f);

    auto stage = [&](int buf, int kt) {
        const short* Ag = Ab + kt * BK;
#pragma unroll
        for (int i = 0; i < BM / 32; ++i) {
            int seg = i * 256 + tid;
            int row = seg >> 3;
            int gcs = (tid & 7) ^ (row & 7);            // pre-swizzled source
            gload_lds16(Ag + (long)row * K + gcs * 8, &As[buf][(i * 256 + w * 64) * 8]);
        }
        const short* Bg = Bb + kt * BK;
#pragma unroll
        for (int i = 0; i < BN / 32; ++i) {
            int seg = i * 256 + tid;
            int row = seg >> 3;
            int gcs = (tid & 7) ^ (row & 7);
            gload_lds16(Bg + (long)row * K + gcs * 8, &Bs[buf][(i * 256 + w * 64) * 8]);
        }
    };

    // prologue: t0 + t1 in flight; wait for t0 only (vmcnt(4) leaves t1 out)
    stage(0, ktBeg);
    stage(1, ktBeg + 1);                 // ktPer >= 12 always
    asm volatile("s_waitcnt vmcnt(4)" ::: "memory");
    __builtin_amdgcn_s_barrier();

    int cur = 0;
    for (int kt = ktBeg; kt < ktEnd; ++kt) {
        // stage t+2 into buffer (cur+2)%3 == (cur-1)%3: everyone finished
        // reading it (barrier at end of previous iteration)
        const bool more = (kt + 2 < ktEnd);
        if (more) stage(cur >= 1 ? cur - 1 : cur + 2, kt + 2);

        const short* Ac = &As[cur][0];
        const short* Bc = &Bs[cur][0];
#pragma unroll
        for (int kk = 0; kk < 2; ++kk) {
            bf16x8 af[FM], bfr[FN];
#pragma unroll
            for (int m = 0; m < FM; ++m) {
                int ar = wr * (BM / 2) + m * 16 + l16;
                int ks = (kk * 4 + lhi) ^ sw;           // ar&7 == sw
                af[m] = *(const bf16x8*)(Ac + ar * BK + ks * 8);
            }
#pragma unroll
            for (int n = 0; n < FN; ++n) {
                int br = wc * (BN / 2) + n * 16 + l16;
                int ks = (kk * 4 + lhi) ^ sw;
                bfr[n] = *(const bf16x8*)(Bc + br * BK + ks * 8);
            }
#pragma unroll
            for (int m = 0; m < FM; ++m)
#pragma unroll
                for (int n = 0; n < FN; ++n)
                    acc[m][n] = __builtin_amdgcn_mfma_f32_16x16x32_bf16(
                        af[m], bfr[n], acc[m][n], 0, 0, 0);
        }
        // steady state: wait oldest stage (t+1) done, t+2 stays in flight
        if (more) asm volatile("s_waitcnt vmcnt(4)" ::: "memory");
        else      asm volatile("s_waitcnt vmcnt(0)" ::: "memory");
        __builtin_amdgcn_s_barrier();
        cur = (cur + 1 == 3) ? 0 : cur + 1;
    }

    // Epilogue. C/D frag mapping: col = lane&15, row = (lane>>4)*4 + reg.
    const int m0 = by * BM, n0 = bx * BN;
#pragma unroll
    for (int m = 0; m < FM; ++m) {
#pragma unroll
        for (int n = 0; n < FN; ++n) {
            const int grow0 = m0 + wr * (BM / 2) + m * 16 + lhi * 4;
            const int gcol  = n0 + wc * (BN / 2) + n * 16 + l16;
#pragma unroll
            for (int r = 0; r < 4; ++r) {
                float val = acc[m][n][r];
                int grow = grow0 + r;
                if constexpr (MODE == 1) {
                    float v = val + bias[gcol];
                    int d  = gcol & 63;
                    int hh = gcol >> 6;                 // 0..35 (uniform per block)
                    int bb = grow >> 9, s = grow & 511;
                    if (hh < 12) {
                        outs0[((long)((bb * 12 + hh) * 512 + s) << 6) + d] = f2b(v * 0.125f);
                    } else if (hh < 24) {
                        outs1[((long)((bb * 12 + (hh - 12)) * 512 + s) << 6) + d] = f2b(v);
                    } else {                             // V stored transposed [B,H,64,512]
                        outs2[((long)((bb * 12 + (hh - 24)) * 64 + d) << 9) + s] = f2b(v);
                    }
                } else if constexpr (MODE == 2) {
                    float v = val + bias[gcol];
                    v = 0.5f * v * (1.0f + erff(v * 0.70710678118f));
                    outs0[(long)grow * N + gcol] = f2b(v);
                } else {                                 // MODE 3: fp32 partial store
                    outf[(long)kz * M * N + (long)grow * N + gcol] = val;
                }
            }
        }
    }
}

// ---------------------------------------------------------------------------
// FFN2 split-K reduce fused with next block's LN1:
//   x += p0 + p1 + b1 ; if DO_LN: lnb = LN(x)*g + be  (one wave per row)
// ---------------------------------------------------------------------------
template<int DO_LN>
__global__ __launch_bounds__(256) void ffn2_reduce_ln(
    const float* __restrict__ part, const float* __restrict__ bias,
    float* __restrict__ x, const float* __restrict__ g,
    const float* __restrict__ be, short* __restrict__ out)
{
    int row  = blockIdx.x * 4 + (threadIdx.x >> 6);
    int lane = threadIdx.x & 63;
    const float4* p0 = (const float4*)part + (long)row * 192;
    const float4* p1 = (const float4*)(part + 2048l * 768) + (long)row * 192;
    const float4* b4 = (const float4*)bias;
    float4* xr = (float4*)(x + (long)row * 768);

    float f[12];
#pragma unroll
    for (int jb = 0; jb < 3; ++jb) {
        int idx = lane + 64 * jb;
        float4 a = p0[idx], b = p1[idx], c = b4[idx], xv = xr[idx];
        xv.x += a.x + b.x + c.x;
        xv.y += a.y + b.y + c.y;
        xv.z += a.z + b.z + c.z;
        xv.w += a.w + b.w + c.w;
        xr[idx] = xv;
        f[4 * jb + 0] = xv.x; f[4 * jb + 1] = xv.y;
        f[4 * jb + 2] = xv.z; f[4 * jb + 3] = xv.w;
    }

    if constexpr (DO_LN) {
        float s = 0.f;
#pragma unroll
        for (int j = 0; j < 12; ++j) s += f[j];
#pragma unroll
        for (int o = 32; o; o >>= 1) s += __shfl_xor(s, o);
        float mu = s * (1.0f / 768.0f);
        float s2 = 0.f;
#pragma unroll
        for (int j = 0; j < 12; ++j) { f[j] -= mu; s2 += f[j] * f[j]; }
#pragma unroll
        for (int o = 32; o; o >>= 1) s2 += __shfl_xor(s2, o);
        float rstd = rsqrtf(s2 * (1.0f / 768.0f) + 1e-5f);

        const float4* gr = (const float4*)g;
        const float4* br = (const float4*)be;
        short4* orow = (short4*)(out + (long)row * 768);
#pragma unroll
        for (int jb = 0; jb < 3; ++jb) {
            float4 gg = gr[lane + 64 * jb], bb = br[lane + 64 * jb];
            short4 o4;
            o4.x = f2b(f[4 * jb + 0] * rstd * gg.x + bb.x);
            o4.y = f2b(f[4 * jb + 1] * rstd * gg.y + bb.y);
            o4.z = f2b(f[4 * jb + 2] * rstd * gg.z + bb.z);
            o4.w = f2b(f[4 * jb + 3] * rstd * gg.w + bb.w);
            orow[lane + 64 * jb] = o4;
        }
    }
}

// ---------------------------------------------------------------------------
// Fused flash attention: one block per (64-row q-tile, z = b*12+h).
// Swapped QK^T (S^T = K·Q^T) so each lane owns a k-slice of ONE q-row
// (q = lane&15) -> online softmax = in-lane reduce + 2 shfl_xor. P re-layouts
// to the PV A-fragment via a per-wave LDS tile. K/V dbuf, 2-phase pipeline.
// Output: x += O (rows/cols exclusive per block -> plain +=).
// ---------------------------------------------------------------------------
__global__ __launch_bounds__(256) void attn_fused(
    const short* __restrict__ Qg,   // [48][512][64] bf16, pre-scaled by 1/8
    const short* __restrict__ Kg,   // [48][512][64]
    const short* __restrict__ VTg,  // [48][64][512]  (V^T per head)
    float* __restrict__ x)          // [2048][768] +=
{
    __shared__ __align__(16) short Qs[64 * 64];        // 8 KB
    __shared__ __align__(16) short Ks[2][64 * 64];     // 16 KB
    __shared__ __align__(16) short Vs[2][64 * 64];     // 16 KB
    __shared__ __align__(16) short Ps[4][16 * 64];     // 8 KB (per-wave P tile)

    const int tid = threadIdx.x;
    const int w = tid >> 6, lane = tid & 63;
    const int l16 = lane & 15, lhi = lane >> 4;

    // XCD grouping: 48 consecutive nf (6 heads) per XCD
    const int f  = blockIdx.y * 8 + blockIdx.x;        // z*8 + qt
    const int nf = (f & 7) * 48 + (f >> 3);
    const int z  = nf >> 3, qt = nf & 7;
    const int q0 = qt * 64;

    const short* Qb = Qg  + (long)z * 512 * 64 + q0 * 64;   // contiguous 64x64
    const short* Kb = Kg  + (long)z * 512 * 64;
    const short* Vb = VTg + (long)z * 64 * 512;

    auto stageQ = [&]() {
#pragma unroll
        for (int i = 0; i < 2; ++i) {
            int seg = i * 256 + tid;
            int row = seg >> 3;
            int gc  = (seg & 7) ^ (row & 7);
            gload_lds16(Qb + row * 64 + gc * 8, Qs + (i * 256 + w * 64) * 8);
        }
    };
    auto stageK = [&](int buf, int kt) {
#pragma unroll
        for (int i = 0; i < 2; ++i) {
            int seg = i * 256 + tid;
            int row = seg >> 3;
            int gc  = (seg & 7) ^ (row & 7);
            gload_lds16(Kb + (kt * 64 + row) * 64 + gc * 8, &Ks[buf][(i * 256 + w * 64) * 8]);
        }
    };
    auto stageV = [&](int buf, int kt) {
#pragma unroll
        for (int i = 0; i < 2; ++i) {
            int seg = i * 256 + tid;
            int row = seg >> 3;                         // d index
            int gc  = (seg & 7) ^ (row & 7);
            gload_lds16(Vb + (long)row * 512 + kt * 64 + gc * 8, &Vs[buf][(i * 256 + w * 64) * 8]);
        }
    };

    stageQ(); stageK(0, 0); stageV(0, 0);
    asm volatile("s_waitcnt vmcnt(0)" ::: "memory");
    __syncthreads();

    // Q b-frags for wave's 16 q-rows (row = w*16 + l16), loaded once
    bf16x8 bq[2];
    {
        int qr = w * 16 + l16;
#pragma unroll
        for (int kk = 0; kk < 2; ++kk)
            bq[kk] = *(const bf16x8*)(Qs + qr * 64 + (((kk * 4 + lhi) ^ (l16 & 7)) * 8));
    }

    float m = -3e38f, l = 0.0f;
    f32x4 acc[4];
#pragma unroll
    for (int bn = 0; bn < 4; ++bn) acc[bn] = (f32x4)(0.0f);

    int cur = 0;
    for (int kt = 0; kt < 8; ++kt) {
        if (kt < 7) { stageK(cur ^ 1, kt + 1); stageV(cur ^ 1, kt + 1); }

        // S^T = K_tile(64 kpos x 64 d) · Q^T : lane holds S[q=l16][k=km*16+lhi*4+r]
        f32x4 s[4];
#pragma unroll
        for (int km = 0; km < 4; ++km) s[km] = (f32x4)(0.0f);
#pragma unroll
        for (int kk = 0; kk < 2; ++kk) {
#pragma unroll
            for (int km = 0; km < 4; ++km) {
                int kr = km * 16 + l16;
                bf16x8 ak = *(const bf16x8*)(&Ks[cur][kr * 64 + (((kk * 4 + lhi) ^ (l16 & 7)) * 8)]);
                s[km] = __builtin_amdgcn_mfma_f32_16x16x32_bf16(ak, bq[kk], s[km], 0, 0, 0);
            }
        }

        // online softmax for q = l16
        float tmax = -3e38f;
#pragma unroll
        for (int km = 0; km < 4; ++km)
#pragma unroll
            for (int r = 0; r < 4; ++r) tmax = fmaxf(tmax, s[km][r]);
        tmax = fmaxf(tmax, __shfl_xor(tmax, 16));
        tmax = fmaxf(tmax, __shfl_xor(tmax, 32));
        float mn = fmaxf(m, tmax);
        float sc = __expf(m - mn);
        float p[16];
        float ts = 0.0f;
#pragma unroll
        for (int km = 0; km < 4; ++km)
#pragma unroll
            for (int r = 0; r < 4; ++r) {
                float e = __expf(s[km][r] - mn);
                p[km * 4 + r] = e; ts += e;
            }
        ts += __shfl_xor(ts, 16);
        ts += __shfl_xor(ts, 32);
        l = l * sc + ts; m = mn;

        // rescale O: acc rows are q = lhi*4+r, sc lives on lane l16==that row
        float scr[4];
#pragma unroll
        for (int r = 0; r < 4; ++r) scr[r] = __shfl(sc, lhi * 4 + r);
#pragma unroll
        for (int bn = 0; bn < 4; ++bn)
#pragma unroll
            for (int r = 0; r < 4; ++r) acc[bn][r] *= scr[r];

        // write P (bf16) to per-wave LDS tile in A-frag layout [q=l16][k]
        {
            short* Pw = &Ps[w][0];
#pragma unroll
            for (int km = 0; km < 4; ++km)
#pragma unroll
                for (int r = 0; r < 4; ++r) {
                    int k = km * 16 + lhi * 4 + r;
                    int g = k >> 3, e = k & 7;
                    Pw[l16 * 64 + ((g ^ (l16 & 7)) * 8) + e] = f2b(p[km * 4 + r]);
                }
        }

        // PV: O(16q x 64d) += P(16q x 64k) · V(64k x 64d)
#pragma unroll
        for (int kk = 0; kk < 2; ++kk) {
            bf16x8 ap = *(const bf16x8*)(&Ps[w][l16 * 64 + (((kk * 4 + lhi) ^ (l16 & 7)) * 8)]);
#pragma unroll
            for (int bn = 0; bn < 4; ++bn) {
                int vr = bn * 16 + l16;
                bf16x8 bv = *(const bf16x8*)(&Vs[cur][vr * 64 + (((kk * 4 + lhi) ^ (l16 & 7)) * 8)]);
                acc[bn] = __builtin_amdgcn_mfma_f32_16x16x32_bf16(ap, bv, acc[bn], 0, 0, 0);
            }
        }

        asm volatile("s_waitcnt vmcnt(0)" ::: "memory");
        __builtin_amdgcn_s_barrier();
        cur ^= 1;
    }

    // epilogue: normalize and accumulate into x
    float inv = 1.0f / l;
    float invr[4];
#pragma unroll
    for (int r = 0; r < 4; ++r) invr[r] = __shfl(inv, lhi * 4 + r);
    const int zb = z / 12, zh = z - (z / 12) * 12;
#pragma unroll
    for (int bn = 0; bn < 4; ++bn)
#pragma unroll
        for (int r = 0; r < 4; ++r) {
            long idx = ((long)(zb * 512 + q0 + w * 16 + lhi * 4 + r)) * 768 + zh * 64 + bn * 16 + l16;
            x[idx] += acc[bn][r] * invr[r];
        }
}

// ---------------------------------------------------------------------------
// LayerNorm: one wave per row (768 fp32), write bf16
// ---------------------------------------------------------------------------
__global__ __launch_bounds__(256) void ln_kernel(
    const float* __restrict__ x, const float* __restrict__ g,
    const float* __restrict__ be, short* __restrict__ out)
{
    int row  = blockIdx.x * 4 + (threadIdx.x >> 6);
    int lane = threadIdx.x & 63;
    const float4* xr = (const float4*)(x + (long)row * 768);
    float4 v0 = xr[lane], v1 = xr[lane + 64], v2 = xr[lane + 128];
    float f[12] = {v0.x, v0.y, v0.z, v0.w, v1.x, v1.y, v1.z, v1.w, v2.x, v2.y, v2.z, v2.w};

    float s = 0.f;
#pragma unroll
    for (int j = 0; j < 12; ++j) s += f[j];
#pragma unroll
    for (int o = 32; o; o >>= 1) s += __shfl_xor(s, o);
    float mu = s * (1.0f / 768.0f);
    float s2 = 0.f;
#pragma unroll
    for (int j = 0; j < 12; ++j) { f[j] -= mu; s2 += f[j] * f[j]; }
#pragma unroll
    for (int o = 32; o; o >>= 1) s2 += __shfl_xor(s2, o);
    float rstd = rsqrtf(s2 * (1.0f / 768.0f) + 1e-5f);

    const float4* gr = (const float4*)g;
    const float4* br = (const float4*)be;
    short4* orow = (short4*)(out + (long)row * 768);
#pragma unroll
    for (int jb = 0; jb < 3; ++jb) {
        float4 gg = gr[lane + 64 * jb], bb = br[lane + 64 * jb];
        short4 o4;
        o4.x = f2b(f[4 * jb + 0] * rstd * gg.x + bb.x);
        o4.y = f2b(f[4 * jb + 1] * rstd * gg.y + bb.y);
        o4.z = f2b(f[4 * jb + 2] * rstd * gg.z + bb.z);
        o4.w = f2b(f[4 * jb + 3] * rstd * gg.w + bb.w);
        orow[lane + 64 * jb] = o4;
    }
}

// ---------------------------------------------------------------------------
// Weight transpose fp32[R,C] -> bf16[C,R]
// ---------------------------------------------------------------------------
__global__ __launch_bounds__(256) void transpose_w(
    const float* __restrict__ in, short* __restrict__ out, int R, int C)
{
    __shared__ float t[32][33];
    int r0 = blockIdx.y * 32, c0 = blockIdx.x * 32;
    int tx = threadIdx.x & 31, ty = threadIdx.x >> 5;
#pragma unroll
    for (int p = 0; p < 4; ++p)
        t[ty + 8 * p][tx] = in[(long)(r0 + ty + 8 * p) * C + c0 + tx];
    __syncthreads();
#pragma unroll
    for (int p = 0; p < 4; ++p)
        out[(long)(c0 + ty + 8 * p) * R + r0 + tx] = f2b(t[tx][ty + 8 * p]);
}

__global__ void concat_bias(const float* __restrict__ bq, const float* __restrict__ bk,
                            const float* __restrict__ bv, float* __restrict__ o)
{
    int i = blockIdx.x * 256 + threadIdx.x;
    if (i < 768) { o[i] = bq[i]; o[768 + i] = bk[i]; o[1536 + i] = bv[i]; }
}

// ---------------------------------------------------------------------------
// Host launcher
// ---------------------------------------------------------------------------
extern "C" void kernel_launch(void* const* d_in, const int* in_sizes, int n_in,
                              void* d_out, int out_size, void* d_ws, size_t ws_size,
                              hipStream_t stream)
{
    (void)in_sizes; (void)n_in; (void)out_size; (void)ws_size;
    const float* x_in = (const float*)d_in[0];
    const float* Wq  = (const float*)d_in[1];
    const float* bq  = (const float*)d_in[2];
    const float* Wk  = (const float*)d_in[3];
    const float* bk  = (const float*)d_in[4];
    const float* Wv  = (const float*)d_in[5];
    const float* bv  = (const float*)d_in[6];
    const float* g1  = (const float*)d_in[7];
    const float* be1 = (const float*)d_in[8];
    const float* g2  = (const float*)d_in[9];
    const float* be2 = (const float*)d_in[10];
    const float* W0  = (const float*)d_in[11];
    const float* b0  = (const float*)d_in[12];
    const float* W1  = (const float*)d_in[13];
    const float* b1  = (const float*)d_in[14];

    float* x = (float*)d_out;   // residual stream lives in d_out, fp32 [2048,768]

    char* ws = (char*)d_ws;
    size_t off = 0;
    auto alloc = [&](size_t bytes) -> char* {
        char* p = ws + off; off = (off + bytes + 255) & ~(size_t)255; return p;
    };
    short* wqkvt = (short*)alloc(2304l * 768 * 2);   // [Wq^T;Wk^T;Wv^T]
    short* w0t   = (short*)alloc(3072l * 768 * 2);
    short* w1t   = (short*)alloc(768l * 3072 * 2);
    float* bqkv  = (float*)alloc(2304 * 4);
    short* lnb   = (short*)alloc(2048l * 768 * 2);   // LN output
    short* q     = (short*)alloc(2048l * 768 * 2);   // [B,H,512,64], pre-scaled 1/8
    short* k     = (short*)alloc(2048l * 768 * 2);   // [B,H,512,64]
    short* vt    = (short*)alloc(2048l * 768 * 2);   // [B,H,64,512]  (V^T)
    short* h     = (short*)alloc(2048l * 3072 * 2);  // FFN hidden
    float* part  = (float*)alloc(2l * 2048 * 768 * 4); // FFN2 split-K partials

    hipMemcpyAsync(x, x_in, 2048l * 768 * 4, hipMemcpyDeviceToDevice, stream);

    transpose_w<<<dim3(24, 24), 256, 0, stream>>>(Wq, wqkvt, 768, 768);
    transpose_w<<<dim3(24, 24), 256, 0, stream>>>(Wk, wqkvt + 768l * 768, 768, 768);
    transpose_w<<<dim3(24, 24), 256, 0, stream>>>(Wv, wqkvt + 2l * 768 * 768, 768, 768);
    transpose_w<<<dim3(96, 24), 256, 0, stream>>>(W0, w0t, 768, 3072);
    transpose_w<<<dim3(24, 96), 256, 0, stream>>>(W1, w1t, 3072, 768);
    concat_bias<<<3, 256, 0, stream>>>(bq, bk, bv, bqkv);

    for (int it = 0; it < 12; ++it) {
        if (it == 0)
            ln_kernel<<<512, 256, 0, stream>>>(x, g1, be1, lnb);
        // QKV projection: 64x64 tiles, 1152 blocks, V written transposed
        gemm_bt<64, 64, 1, 1><<<dim3(36, 32, 1), 256, 0, stream>>>(
            lnb, wqkvt, bqkv, nullptr, q, k, vt, 0, 0, 0, 2048, 2304, 768);
        // fused flash attention: x += softmax(q k^T) v
        attn_fused<<<dim3(8, 48), 256, 0, stream>>>(q, k, vt, x);
        ln_kernel<<<512, 256, 0, stream>>>(x, g2, be2, lnb);
        // h = gelu(ln2 @ W0 + b0): 64x64 tiles, 1536 blocks
        gemm_bt<64, 64, 2, 1><<<dim3(48, 32, 1), 256, 0, stream>>>(
            lnb, w0t, b0, nullptr, h, nullptr, nullptr, 0, 0, 0, 2048, 3072, 768);
        // FFN2: split-K=2 fp32 partials (no atomics), 768 blocks
        gemm_bt<64, 64, 3, 2><<<dim3(12, 32, 2), 256, 0, stream>>>(
            h, w1t, nullptr, part, nullptr, nullptr, nullptr, 0, 0, 0, 2048, 768, 3072);
        // x += p0 + p1 + b1, fused with LN1 of the next block
        if (it < 11)
            ffn2_reduce_ln<1><<<512, 256, 0, stream>>>(part, b1, x, g1, be1, lnb);
        else
            ffn2_reduce_ln<0><<<512, 256, 0, stream>>>(part, b1, x, nullptr, nullptr, nullptr);
    }
}